// Round 4
// baseline (182.702 us; speedup 1.0000x reference)
//
#include <hip/hip_runtime.h>

// ---------------------------------------------------------------------------
// Sparse3DNA: x->QKV proj (bf16 MFMA GEMM), 3x3x3 causal window attention
// (+BOS), output proj. Shapes: b=2, T=4096 (4x32x32), DIM=512, 8 heads x 64.
// R4: barrier-free direct-fragment GEMM (no LDS) — K=512 is too short for the
// m97 2-barrier structure (16 steps x ~600cyc vmcnt(0) drain); operands are
// L2/L3-resident so per-wave register pipelining beats LDS staging.
// ---------------------------------------------------------------------------

#define T_TOK   4096
#define DIM     512
#define NQKV    1536

typedef unsigned short u16;
typedef unsigned int   u32;
typedef unsigned long long u64;
typedef __attribute__((ext_vector_type(8))) short short8;   // 8 bf16 (4 VGPR)
typedef __attribute__((ext_vector_type(4))) float f32x4;

__device__ __forceinline__ u16 f2bf(float f) {           // RNE float->bf16
    u32 u = __float_as_uint(f);
    return (u16)((u + 0x7fffu + ((u >> 16) & 1u)) >> 16);
}
__device__ __forceinline__ float b2f(u16 u) {
    return __uint_as_float(((u32)u) << 16);
}

// ---------------------------------------------------------------------------
// merged cast kernel.
//  blocks [0,4096): x fp32 -> bf16 (vectorized)
//  blocks [4096,4288): Wt[n][k] = [Wq|Wk|Wv](k,n), LDS-tiled 64x64 transpose
//  blocks [4288,4352): Wot[n][k] = Wo[k][n], same
// ---------------------------------------------------------------------------
__global__ void cast_all_kernel(const float4* __restrict__ x,
                                const float* __restrict__ Wq, const float* __restrict__ Wkv,
                                const float* __restrict__ Wo,
                                u16* __restrict__ xb, u16* __restrict__ Wt,
                                u16* __restrict__ Wot) {
    __shared__ float S[64 * 65];
    int blk = blockIdx.x;
    int tid = threadIdx.x;
    if (blk < 4096) {
        int i = blk * 256 + tid;                  // 1,048,576 float4s
        float4 v = x[i];
        u64 pack = (u64)f2bf(v.x) | ((u64)f2bf(v.y) << 16) |
                   ((u64)f2bf(v.z) << 32) | ((u64)f2bf(v.w) << 48);
        ((u64*)xb)[i] = pack;
        return;
    }
    int isWo = blk >= 4288;
    int tIdx = isWo ? (blk - 4288) : (blk - 4096);
    int tn = tIdx >> 3, tk = tIdx & 7;            // n-tile, k-tile
    #pragma unroll
    for (int p = 0; p < 16; ++p) {                // stage, coalesced over n
        int kl = p * 4 + (tid >> 6), nl = tid & 63;
        int gk = tk * 64 + kl, gn = tn * 64 + nl;
        float v;
        if (isWo)            v = Wo[gk * 512 + gn];
        else if (gn < 512)   v = Wq[gk * 512 + gn];
        else                 v = Wkv[gk * 1024 + (gn - 512)];
        S[kl * 65 + nl] = v;
    }
    __syncthreads();
    u16* dst = isWo ? Wot : Wt;
    #pragma unroll
    for (int p = 0; p < 16; ++p) {                // write, coalesced over k
        int nl = p * 4 + (tid >> 6), kl = tid & 63;
        dst[(size_t)(tn * 64 + nl) * 512 + tk * 64 + kl] = f2bf(S[kl * 65 + nl]);
    }
}

// ---------------------------------------------------------------------------
// Direct-fragment NT GEMM: C(MxN) = A(MxK) * B(NxK)^T, K=512, bf16, fp32 acc.
// No LDS, no barriers. BMxBN per block, 4 waves (2x2), wave tile
// (BM/2)x(BN/2) via mfma 16x16x32. Fragment = 16B/lane dwordx4 straight from
// global: row = tile_row + mrow, bytes [quad*16, quad*16+16) of the 64B
// K-step strip (A and B identical indexing in NT layout, m92 pattern).
// Per-step addresses are imm offsets (step*64B); loads pipelined 1 step
// ahead in registers; compiler emits per-wave fine-grained vmcnt — no
// vmcnt(0) barrier drain anywhere in the K-loop.
// MODE 0: bf16 store. MODE 1: fp32 store + bias.
// ---------------------------------------------------------------------------
template <int BM, int BN, int MODE>
__global__ __launch_bounds__(256, 3)
void gemm_direct(const u16* __restrict__ A, const u16* __restrict__ B,
                 void* __restrict__ Cv, const float* __restrict__ bias,
                 int lda, int ldb, int ldc) {
    constexpr int KSTEPS = 16;                   // K = 512 = 16 x 32
    constexpr int MI = BM / 32, NJ = BN / 32;
    const int lane = threadIdx.x & 63, wave = threadIdx.x >> 6;
    const int quad = lane >> 4, mrow = lane & 15;
    const int wm = wave >> 1, wn = wave & 1;
    const int bm = blockIdx.y, bn = blockIdx.x;

    const short8* aP[MI];
    const short8* bP[NJ];
    #pragma unroll
    for (int i = 0; i < MI; ++i) {
        int row = bm * BM + wm * (BM / 2) + i * 16 + mrow;
        aP[i] = (const short8*)(A + (size_t)row * lda + quad * 8);
    }
    #pragma unroll
    for (int j = 0; j < NJ; ++j) {
        int row = bn * BN + wn * (BN / 2) + j * 16 + mrow;
        bP[j] = (const short8*)(B + (size_t)row * ldb + quad * 8);
    }

    f32x4 acc[MI][NJ] = {};
    short8 aC[MI], bC[NJ], aN[MI], bN[NJ];
    #pragma unroll
    for (int i = 0; i < MI; ++i) aC[i] = aP[i][0];
    #pragma unroll
    for (int j = 0; j < NJ; ++j) bC[j] = bP[j][0];

    #pragma unroll 4
    for (int ks = 0; ks < KSTEPS; ++ks) {
        if (ks + 1 < KSTEPS) {                   // prefetch next K-step
            #pragma unroll
            for (int i = 0; i < MI; ++i) aN[i] = aP[i][(ks + 1) * 4];
            #pragma unroll
            for (int j = 0; j < NJ; ++j) bN[j] = bP[j][(ks + 1) * 4];
        }
        #pragma unroll
        for (int i = 0; i < MI; ++i)
            #pragma unroll
            for (int j = 0; j < NJ; ++j)
                acc[i][j] = __builtin_amdgcn_mfma_f32_16x16x32_bf16(aC[i], bC[j], acc[i][j], 0, 0, 0);
        #pragma unroll
        for (int i = 0; i < MI; ++i) aC[i] = aN[i];
        #pragma unroll
        for (int j = 0; j < NJ; ++j) bC[j] = bN[j];
    }

    // epilogue: D row = quad*4 + reg, col = lane&15 (m89-verified layout)
    #pragma unroll
    for (int i = 0; i < MI; ++i) {
        #pragma unroll
        for (int j = 0; j < NJ; ++j) {
            int colg = bn * BN + wn * (BN / 2) + j * 16 + mrow;
            #pragma unroll
            for (int r = 0; r < 4; ++r) {
                int rowg = bm * BM + wm * (BM / 2) + i * 16 + quad * 4 + r;
                if (MODE == 0) {
                    ((u16*)Cv)[(size_t)rowg * ldc + colg] = f2bf(acc[i][j][r]);
                } else {
                    ((float*)Cv)[(size_t)rowg * ldc + colg] = acc[i][j][r] + bias[colg];
                }
            }
        }
    }
}

// ---------------------------------------------------------------------------
// Attention: one wave per (b, h, ti).  Two-phase, branch-free slot set.
// Valid neighbor offsets (causal nb<=t <=> (df,dh,dw) lex<= 0): 9x df=-1,
// 3x (0,-1,dw), (0,0,-1), (0,0,0)  => 14 window slots + BOS = 15 (+1 pad).
// Phase 1: lane = j*4+g; 16-dim partial dot, 2-shfl reduce, batched softmax
//   (4-shfl max, ONE exp, 4-shfl sum), pe normalized by rcp(l).
// Phase 2: lane = dim; 15x (2 readlane + u16 load + fma), u32 byte offsets.
// ---------------------------------------------------------------------------
__global__ __launch_bounds__(256)
void attn_kernel(const u16* __restrict__ QKV, u16* __restrict__ O) {
    const int wid  = blockIdx.x * 4 + (threadIdx.x >> 6);
    const int lane = threadIdx.x & 63;
    const int bh = wid >> 12;            // 16
    const int ti = wid & 4095;           // 4096
    const int b = bh >> 3, h = bh & 7;
    const size_t baseQ = (size_t)b * T_TOK * NQKV;
    const size_t baseO = (size_t)b * T_TOK * DIM;

    if (ti == 0) {                        // output row 0 = bos_v
        O[baseO + h * 64 + lane] = QKV[baseQ + 1024 + h * 64 + lane];
        return;
    }
    const int t = ti - 1;                 // grid position, 0..4094
    const int f = t >> 10, hh = (t >> 5) & 31, ww = t & 31;

    const int j = lane >> 2, g = lane & 3;
    int jm1 = j - 1;
    int dh9 = ((jm1 * 11) >> 5) - 1;      // j in 1..9: (j-1)/3 - 1
    int dw9 = jm1 - (dh9 + 1) * 3 - 1;    // j in 1..9: (j-1)%3 - 1
    int df = (j >= 1 && j <= 9) ? -1 : 0;
    int dh = (j >= 1 && j <= 9) ? dh9 : ((j >= 10 && j <= 12) ? -1 : 0);
    int dw = (j >= 1 && j <= 9) ? dw9 :
             ((j >= 10 && j <= 12) ? (j - 11) : ((j == 13) ? -1 : 0));
    int nf = f + df, nh = hh + dh, nw = ww + dw;
    int valid = (nf >= 0) && ((unsigned)nh < 32u) && ((unsigned)nw < 32u)
                && (j >= 1) && (j <= 14);
    int p = valid ? (t + 1 + df * 1024 + dh * 32 + dw) : 0;   // j==0 -> BOS
    int score_on = valid || (j == 0);

    // ---- phase 1: scores
    const u16* qrow = QKV + baseQ + (size_t)(t + 1) * NQKV + h * 64 + g * 16;
    short8 q0 = *(const short8*)qrow;
    short8 q1 = *(const short8*)(qrow + 8);
    const u16* krow = QKV + baseQ + (size_t)p * NQKV + 512 + h * 64 + g * 16;
    short8 k0 = *(const short8*)krow;
    short8 k1 = *(const short8*)(krow + 8);
    float s = 0.f;
    #pragma unroll
    for (int i = 0; i < 8; ++i) {
        s = fmaf(b2f((u16)q0[i]), b2f((u16)k0[i]), s);
        s = fmaf(b2f((u16)q1[i]), b2f((u16)k1[i]), s);
    }
    s += __shfl_xor(s, 1);
    s += __shfl_xor(s, 2);                // all 4 g-lanes of slot j hold dot_j
    s *= 0.125f;                          // SCALE
    s = score_on ? s : -3.0e38f;

    float m = s;
    #pragma unroll
    for (int off = 4; off <= 32; off <<= 1) m = fmaxf(m, __shfl_xor(m, off));
    float pe = __expf(s - m);             // masked lanes -> 0
    float l = pe;
    #pragma unroll
    for (int off = 4; off <= 32; off <<= 1) l += __shfl_xor(l, off);
    float pen = pe * __frcp_rn(l);        // normalized weight, wave-wide
    u32 voff = (u32)p * 3072u;            // byte offset of V row p

    // ---- phase 2: PV, lane = dim
    float acc = 0.f;
    const char* vb = (const char*)(QKV + baseQ + 1024 + h * 64 + lane);
    #pragma unroll
    for (int jj = 0; jj < 15; ++jj) {
        u32 o = (u32)__builtin_amdgcn_readlane((int)voff, jj * 4);
        float pj = __uint_as_float(
                     (u32)__builtin_amdgcn_readlane((int)__float_as_uint(pen), jj * 4));
        float vv = b2f(*(const u16*)(vb + o));
        acc = fmaf(pj, vv, acc);
    }
    O[baseO + (size_t)ti * DIM + h * 64 + lane] = f2bf(acc);
}

// ---------------------------------------------------------------------------
// launch: cast -> gemm1 (QKV) -> attn -> gemm2 (out proj + bias)
// ws layout (bytes): xb 8M @0 | Wt 1.5M @8388608 | Wot 0.5M @9961472 |
//                    QKV 24M @10485760 | O aliases xb @0   (total ~34MB)
// ---------------------------------------------------------------------------
extern "C" void kernel_launch(void* const* d_in, const int* in_sizes, int n_in,
                              void* d_out, int out_size, void* d_ws, size_t ws_size,
                              hipStream_t stream) {
    const float* x   = (const float*)d_in[0];
    const float* Wq  = (const float*)d_in[1];
    const float* Wkv = (const float*)d_in[2];
    const float* Wo  = (const float*)d_in[3];
    const float* bo  = (const float*)d_in[4];
    float* out = (float*)d_out;
    char* ws = (char*)d_ws;

    u16* xb  = (u16*)(ws + 0);
    u16* Wt  = (u16*)(ws + 8388608);
    u16* Wot = (u16*)(ws + 9961472);
    u16* QKV = (u16*)(ws + 10485760);
    u16* O   = (u16*)(ws + 0);          // aliases xb (dead after gemm1)

    cast_all_kernel<<<dim3(4352), dim3(256), 0, stream>>>(
        (const float4*)x, Wq, Wkv, Wo, xb, Wt, Wot);
    gemm_direct<128, 128, 0><<<dim3(12, 64), dim3(256), 0, stream>>>(
        xb, Wt, (void*)QKV, nullptr, 512, 512, 1536);
    attn_kernel<<<dim3(16384), dim3(256), 0, stream>>>(QKV, O);
    gemm_direct<128, 64, 1><<<dim3(8, 64), dim3(256), 0, stream>>>(
        O, Wot, (void*)out, bo, 512, 512, 512);
}

// Round 5
// 141.550 us; speedup vs baseline: 1.2907x; 1.2907x over previous
//
#include <hip/hip_runtime.h>

// ---------------------------------------------------------------------------
// Sparse3DNA: x->QKV proj (bf16 MFMA GEMM), 3x3x3 causal window attention
// (+BOS), output proj. Shapes: b=2, T=4096 (4x32x32), DIM=512, 8 heads x 64.
// R5: back to LDS-staged gemm_nt (direct-fragment R4 was latency-bound:
// MfmaUtil 8%, occ 28%); BK=64 halves the per-step vmcnt(0) barrier drains
// (16 -> 8 steps at K=512).
// ---------------------------------------------------------------------------

#define T_TOK   4096
#define DIM     512
#define NQKV    1536

typedef unsigned short u16;
typedef unsigned int   u32;
typedef unsigned long long u64;
typedef __attribute__((ext_vector_type(8))) short short8;   // 8 bf16 (4 VGPR)
typedef __attribute__((ext_vector_type(4))) float f32x4;

__device__ __forceinline__ u16 f2bf(float f) {           // RNE float->bf16
    u32 u = __float_as_uint(f);
    return (u16)((u + 0x7fffu + ((u >> 16) & 1u)) >> 16);
}
__device__ __forceinline__ float b2f(u16 u) {
    return __uint_as_float(((u32)u) << 16);
}

__device__ __forceinline__ void gload_lds16(const void* g, void* l) {
    // async global->LDS, 16B/lane; LDS dest = wave-uniform base + lane*16
    __builtin_amdgcn_global_load_lds(
        (const __attribute__((address_space(1))) void*)g,
        (__attribute__((address_space(3))) void*)l, 16, 0, 0);
}

// ---------------------------------------------------------------------------
// merged cast kernel.
//  blocks [0,4096): x fp32 -> bf16 (vectorized)
//  blocks [4096,4288): Wt[n][k] = [Wq|Wk|Wv](k,n), LDS-tiled 64x64 transpose
//  blocks [4288,4352): Wot[n][k] = Wo[k][n], same
// ---------------------------------------------------------------------------
__global__ void cast_all_kernel(const float4* __restrict__ x,
                                const float* __restrict__ Wq, const float* __restrict__ Wkv,
                                const float* __restrict__ Wo,
                                u16* __restrict__ xb, u16* __restrict__ Wt,
                                u16* __restrict__ Wot) {
    __shared__ float S[64 * 65];
    int blk = blockIdx.x;
    int tid = threadIdx.x;
    if (blk < 4096) {
        int i = blk * 256 + tid;                  // 1,048,576 float4s
        float4 v = x[i];
        u64 pack = (u64)f2bf(v.x) | ((u64)f2bf(v.y) << 16) |
                   ((u64)f2bf(v.z) << 32) | ((u64)f2bf(v.w) << 48);
        ((u64*)xb)[i] = pack;
        return;
    }
    int isWo = blk >= 4288;
    int tIdx = isWo ? (blk - 4288) : (blk - 4096);
    int tn = tIdx >> 3, tk = tIdx & 7;            // n-tile, k-tile
    #pragma unroll
    for (int p = 0; p < 16; ++p) {                // stage, coalesced over n
        int kl = p * 4 + (tid >> 6), nl = tid & 63;
        int gk = tk * 64 + kl, gn = tn * 64 + nl;
        float v;
        if (isWo)            v = Wo[gk * 512 + gn];
        else if (gn < 512)   v = Wq[gk * 512 + gn];
        else                 v = Wkv[gk * 1024 + (gn - 512)];
        S[kl * 65 + nl] = v;
    }
    __syncthreads();
    u16* dst = isWo ? Wot : Wt;
    #pragma unroll
    for (int p = 0; p < 16; ++p) {                // write, coalesced over k
        int nl = p * 4 + (tid >> 6), kl = tid & 63;
        dst[(size_t)(tn * 64 + nl) * 512 + tk * 64 + kl] = f2bf(S[kl * 65 + nl]);
    }
}

// ---------------------------------------------------------------------------
// NT GEMM: C(MxN) = A(MxK) * B(NxK)^T, K=512, bf16 in, fp32 acc.
// BMxBN tile / block, 4 waves (2x2), wave tile (BM/2)x(BN/2), mfma 16x16x32.
// LDS XOR-swizzle (CPR = BK/8 16B-chunks per row):
//   slot(r, kc) = r*CPR + ((kc + (r>>1)) & (CPR-1))
// Fragment ds_read_b128 (16 rows x chunk pos): bank = 4*pos mod 32; swz
// spreads 16 rows over CPR positions -> 2 lanes/bank = conflict-free (m136).
// MODE 0: bf16 store. MODE 1: fp32 store + bias.
// ---------------------------------------------------------------------------
template <int BM, int BN, int BK, int MODE>
__global__ __launch_bounds__(256)
void gemm_nt(const u16* __restrict__ A, const u16* __restrict__ B,
             void* __restrict__ Cv, const float* __restrict__ bias,
             int lda, int ldb, int ldc) {
    constexpr int K = 512;
    constexpr int CPR = BK / 8;                  // 16B chunks per row
    constexpr int ACH = BM * CPR;                // A chunks per K-step
    constexpr int NCH = (BM + BN) * CPR;
    constexpr int NLD = NCH / 256;               // chunks per thread
    constexpr int ABYTES = BM * BK * 2;
    constexpr int KSUB = BK / 32;                // mfma k-substeps
    constexpr int MI = BM / 32, NJ = BN / 32;    // acc tiles per wave
    __shared__ __align__(16) char lds[(BM + BN) * BK * 2];
    const int tid  = threadIdx.x;
    const int lane = tid & 63, wave = tid >> 6;
    const int quad = lane >> 4, mrow = lane & 15;
    const int wm = wave >> 1, wn = wave & 1;
    const int bm = blockIdx.y, bn = blockIdx.x;

    const char* gptr[NLD];
    char*       lptr[NLD];
    #pragma unroll
    for (int it = 0; it < NLD; ++it) {
        int c   = it * 256 + tid;                // chunk id, lane-consecutive
        int inB = (c >= ACH);
        int a   = inB ? c - ACH : c;
        int r   = a / CPR;                       // tile row
        int kcs = a & (CPR - 1);
        int kc  = (kcs - (r >> 1)) & (CPR - 1);  // inverse swizzle
        int row = (inB ? bn * BN : bm * BM) + r;
        const u16* base = inB ? B : A;
        int ld = inB ? ldb : lda;
        gptr[it] = (const char*)(base + (size_t)row * ld + kc * 8);
        lptr[it] = (char*)lds + (it * 256 + wave * 64) * 16;   // wave-uniform
    }
    const short8* aLds[MI][KSUB];
    const short8* bLds[NJ][KSUB];
    #pragma unroll
    for (int i = 0; i < MI; ++i) {
        int ra = wm * (BM / 2) + i * 16 + mrow;
        #pragma unroll
        for (int ks = 0; ks < KSUB; ++ks)
            aLds[i][ks] = (const short8*)(lds +
                (ra * CPR + ((ks * 4 + quad + (ra >> 1)) & (CPR - 1))) * 16);
    }
    #pragma unroll
    for (int j = 0; j < NJ; ++j) {
        int rb = wn * (BN / 2) + j * 16 + mrow;
        #pragma unroll
        for (int ks = 0; ks < KSUB; ++ks)
            bLds[j][ks] = (const short8*)(lds + ABYTES +
                (rb * CPR + ((ks * 4 + quad + (rb >> 1)) & (CPR - 1))) * 16);
    }

    f32x4 acc[MI][NJ] = {};
    for (int k0 = 0; k0 < K; k0 += BK) {
        #pragma unroll
        for (int it = 0; it < NLD; ++it)
            gload_lds16(gptr[it] + 2 * k0, lptr[it]);
        __syncthreads();
        #pragma unroll
        for (int ks = 0; ks < KSUB; ++ks) {
            short8 af[MI], bf[NJ];
            #pragma unroll
            for (int i = 0; i < MI; ++i) af[i] = *aLds[i][ks];
            #pragma unroll
            for (int j = 0; j < NJ; ++j) bf[j] = *bLds[j][ks];
            #pragma unroll
            for (int i = 0; i < MI; ++i)
                #pragma unroll
                for (int j = 0; j < NJ; ++j)
                    acc[i][j] = __builtin_amdgcn_mfma_f32_16x16x32_bf16(af[i], bf[j], acc[i][j], 0, 0, 0);
        }
        __syncthreads();
    }

    // epilogue: D row = quad*4 + reg, col = lane&15 (m89-verified layout)
    #pragma unroll
    for (int i = 0; i < MI; ++i) {
        #pragma unroll
        for (int j = 0; j < NJ; ++j) {
            int colg = bn * BN + wn * (BN / 2) + j * 16 + mrow;
            #pragma unroll
            for (int r = 0; r < 4; ++r) {
                int rowg = bm * BM + wm * (BM / 2) + i * 16 + quad * 4 + r;
                if (MODE == 0) {
                    ((u16*)Cv)[(size_t)rowg * ldc + colg] = f2bf(acc[i][j][r]);
                } else {
                    ((float*)Cv)[(size_t)rowg * ldc + colg] = acc[i][j][r] + bias[colg];
                }
            }
        }
    }
}

// ---------------------------------------------------------------------------
// Attention: one wave per (b, h, ti).  Two-phase, branch-free slot set.
// Valid neighbor offsets (causal nb<=t <=> (df,dh,dw) lex<= 0): 9x df=-1,
// 3x (0,-1,dw), (0,0,-1), (0,0,0)  => 14 window slots + BOS = 15 (+1 pad).
// Phase 1: lane = j*4+g; 16-dim partial dot, 2-shfl reduce, batched softmax
//   (4-shfl max, ONE exp, 4-shfl sum), pe normalized by rcp(l).
// Phase 2: lane = dim; 15x (2 readlane + u16 load + fma), u32 byte offsets.
// ---------------------------------------------------------------------------
__global__ __launch_bounds__(256)
void attn_kernel(const u16* __restrict__ QKV, u16* __restrict__ O) {
    const int wid  = blockIdx.x * 4 + (threadIdx.x >> 6);
    const int lane = threadIdx.x & 63;
    const int bh = wid >> 12;            // 16
    const int ti = wid & 4095;           // 4096
    const int b = bh >> 3, h = bh & 7;
    const size_t baseQ = (size_t)b * T_TOK * NQKV;
    const size_t baseO = (size_t)b * T_TOK * DIM;

    if (ti == 0) {                        // output row 0 = bos_v
        O[baseO + h * 64 + lane] = QKV[baseQ + 1024 + h * 64 + lane];
        return;
    }
    const int t = ti - 1;                 // grid position, 0..4094
    const int f = t >> 10, hh = (t >> 5) & 31, ww = t & 31;

    const int j = lane >> 2, g = lane & 3;
    int jm1 = j - 1;
    int dh9 = ((jm1 * 11) >> 5) - 1;      // j in 1..9: (j-1)/3 - 1
    int dw9 = jm1 - (dh9 + 1) * 3 - 1;    // j in 1..9: (j-1)%3 - 1
    int df = (j >= 1 && j <= 9) ? -1 : 0;
    int dh = (j >= 1 && j <= 9) ? dh9 : ((j >= 10 && j <= 12) ? -1 : 0);
    int dw = (j >= 1 && j <= 9) ? dw9 :
             ((j >= 10 && j <= 12) ? (j - 11) : ((j == 13) ? -1 : 0));
    int nf = f + df, nh = hh + dh, nw = ww + dw;
    int valid = (nf >= 0) && ((unsigned)nh < 32u) && ((unsigned)nw < 32u)
                && (j >= 1) && (j <= 14);
    int p = valid ? (t + 1 + df * 1024 + dh * 32 + dw) : 0;   // j==0 -> BOS
    int score_on = valid || (j == 0);

    // ---- phase 1: scores
    const u16* qrow = QKV + baseQ + (size_t)(t + 1) * NQKV + h * 64 + g * 16;
    short8 q0 = *(const short8*)qrow;
    short8 q1 = *(const short8*)(qrow + 8);
    const u16* krow = QKV + baseQ + (size_t)p * NQKV + 512 + h * 64 + g * 16;
    short8 k0 = *(const short8*)krow;
    short8 k1 = *(const short8*)(krow + 8);
    float s = 0.f;
    #pragma unroll
    for (int i = 0; i < 8; ++i) {
        s = fmaf(b2f((u16)q0[i]), b2f((u16)k0[i]), s);
        s = fmaf(b2f((u16)q1[i]), b2f((u16)k1[i]), s);
    }
    s += __shfl_xor(s, 1);
    s += __shfl_xor(s, 2);                // all 4 g-lanes of slot j hold dot_j
    s *= 0.125f;                          // SCALE
    s = score_on ? s : -3.0e38f;

    float m = s;
    #pragma unroll
    for (int off = 4; off <= 32; off <<= 1) m = fmaxf(m, __shfl_xor(m, off));
    float pe = __expf(s - m);             // masked lanes -> 0
    float l = pe;
    #pragma unroll
    for (int off = 4; off <= 32; off <<= 1) l += __shfl_xor(l, off);
    float pen = pe * __frcp_rn(l);        // normalized weight, wave-wide
    u32 voff = (u32)p * 3072u;            // byte offset of V row p

    // ---- phase 2: PV, lane = dim
    float acc = 0.f;
    const char* vb = (const char*)(QKV + baseQ + 1024 + h * 64 + lane);
    #pragma unroll
    for (int jj = 0; jj < 15; ++jj) {
        u32 o = (u32)__builtin_amdgcn_readlane((int)voff, jj * 4);
        float pj = __uint_as_float(
                     (u32)__builtin_amdgcn_readlane((int)__float_as_uint(pen), jj * 4));
        float vv = b2f(*(const u16*)(vb + o));
        acc = fmaf(pj, vv, acc);
    }
    O[baseO + (size_t)ti * DIM + h * 64 + lane] = f2bf(acc);
}

// ---------------------------------------------------------------------------
// launch: cast -> gemm1 (QKV) -> attn -> gemm2 (out proj + bias)
// ws layout (bytes): xb 8M @0 | Wt 1.5M @8388608 | Wot 0.5M @9961472 |
//                    QKV 24M @10485760 | O aliases xb @0   (total ~34MB)
// ---------------------------------------------------------------------------
extern "C" void kernel_launch(void* const* d_in, const int* in_sizes, int n_in,
                              void* d_out, int out_size, void* d_ws, size_t ws_size,
                              hipStream_t stream) {
    const float* x   = (const float*)d_in[0];
    const float* Wq  = (const float*)d_in[1];
    const float* Wkv = (const float*)d_in[2];
    const float* Wo  = (const float*)d_in[3];
    const float* bo  = (const float*)d_in[4];
    float* out = (float*)d_out;
    char* ws = (char*)d_ws;

    u16* xb  = (u16*)(ws + 0);
    u16* Wt  = (u16*)(ws + 8388608);
    u16* Wot = (u16*)(ws + 9961472);
    u16* QKV = (u16*)(ws + 10485760);
    u16* O   = (u16*)(ws + 0);          // aliases xb (dead after gemm1)

    cast_all_kernel<<<dim3(4352), dim3(256), 0, stream>>>(
        (const float4*)x, Wq, Wkv, Wo, xb, Wt, Wot);
    gemm_nt<128, 128, 64, 0><<<dim3(12, 64), dim3(256), 0, stream>>>(
        xb, Wt, (void*)QKV, nullptr, 512, 512, 1536);
    attn_kernel<<<dim3(16384), dim3(256), 0, stream>>>(QKV, O);
    gemm_nt<128, 64, 64, 1><<<dim3(8, 64), dim3(256), 0, stream>>>(
        O, Wot, (void*)out, bo, 512, 512, 512);
}

// Round 6
// 138.844 us; speedup vs baseline: 1.3159x; 1.0195x over previous
//
#include <hip/hip_runtime.h>

// ---------------------------------------------------------------------------
// Sparse3DNA: x->QKV proj (bf16 MFMA GEMM), 3x3x3 causal window attention
// (+BOS), output proj. Shapes: b=2, T=4096 (4x32x32), DIM=512, 8 heads x 64.
// R6: double-buffered LDS GEMM with raw s_barrier + s_waitcnt vmcnt(NLD) —
// next stage's global_load_lds stays in flight across the barrier (AITER
// pattern); removes the per-K-step vmcnt(0) drain of __syncthreads.
// ---------------------------------------------------------------------------

#define T_TOK   4096
#define DIM     512
#define NQKV    1536

typedef unsigned short u16;
typedef unsigned int   u32;
typedef unsigned long long u64;
typedef __attribute__((ext_vector_type(8))) short short8;   // 8 bf16 (4 VGPR)
typedef __attribute__((ext_vector_type(4))) float f32x4;

__device__ __forceinline__ u16 f2bf(float f) {           // RNE float->bf16
    u32 u = __float_as_uint(f);
    return (u16)((u + 0x7fffu + ((u >> 16) & 1u)) >> 16);
}
__device__ __forceinline__ float b2f(u16 u) {
    return __uint_as_float(((u32)u) << 16);
}

__device__ __forceinline__ void gload_lds16(const void* g, void* l) {
    // async global->LDS, 16B/lane; LDS dest = wave-uniform base + lane*16
    __builtin_amdgcn_global_load_lds(
        (const __attribute__((address_space(1))) void*)g,
        (__attribute__((address_space(3))) void*)l, 16, 0, 0);
}

// ---------------------------------------------------------------------------
// merged cast kernel.
//  blocks [0,4096): x fp32 -> bf16 (vectorized)
//  blocks [4096,4288): Wt[n][k] = [Wq|Wk|Wv](k,n), LDS-tiled 64x64 transpose
//  blocks [4288,4352): Wot[n][k] = Wo[k][n], same
// ---------------------------------------------------------------------------
__global__ void cast_all_kernel(const float4* __restrict__ x,
                                const float* __restrict__ Wq, const float* __restrict__ Wkv,
                                const float* __restrict__ Wo,
                                u16* __restrict__ xb, u16* __restrict__ Wt,
                                u16* __restrict__ Wot) {
    __shared__ float S[64 * 65];
    int blk = blockIdx.x;
    int tid = threadIdx.x;
    if (blk < 4096) {
        int i = blk * 256 + tid;                  // 1,048,576 float4s
        float4 v = x[i];
        u64 pack = (u64)f2bf(v.x) | ((u64)f2bf(v.y) << 16) |
                   ((u64)f2bf(v.z) << 32) | ((u64)f2bf(v.w) << 48);
        ((u64*)xb)[i] = pack;
        return;
    }
    int isWo = blk >= 4288;
    int tIdx = isWo ? (blk - 4288) : (blk - 4096);
    int tn = tIdx >> 3, tk = tIdx & 7;            // n-tile, k-tile
    #pragma unroll
    for (int p = 0; p < 16; ++p) {                // stage, coalesced over n
        int kl = p * 4 + (tid >> 6), nl = tid & 63;
        int gk = tk * 64 + kl, gn = tn * 64 + nl;
        float v;
        if (isWo)            v = Wo[gk * 512 + gn];
        else if (gn < 512)   v = Wq[gk * 512 + gn];
        else                 v = Wkv[gk * 1024 + (gn - 512)];
        S[kl * 65 + nl] = v;
    }
    __syncthreads();
    u16* dst = isWo ? Wot : Wt;
    #pragma unroll
    for (int p = 0; p < 16; ++p) {                // write, coalesced over k
        int nl = p * 4 + (tid >> 6), kl = tid & 63;
        dst[(size_t)(tn * 64 + nl) * 512 + tk * 64 + kl] = f2bf(S[kl * 65 + nl]);
    }
}

// ---------------------------------------------------------------------------
// NT GEMM, double-buffered: C(MxN) = A(MxK) * B(NxK)^T, K=512, bf16, fp32 acc.
// BMxBN / block, 4 waves (2x2), wave tile (BM/2)x(BN/2), mfma 16x16x32, BK=32.
// LDS XOR-swizzle: slot(r,kc) = r*4 + ((kc + (r>>1)) & 3) -> ds_read_b128
// lands 2 lanes/bank (free, m136).  K-loop per step:
//   stage(ks+1 -> buf^1)                  (NLD async loads, in flight)
//   s_waitcnt vmcnt(NLD); s_barrier       (wait ONLY stage ks; prefetch rides)
//   ds_read frags(buf) + 16 MFMA
//   s_barrier                             (all waves done reading buf)
// MODE 0: bf16 store. MODE 1: fp32 store + bias.
// ---------------------------------------------------------------------------
template <int BM, int BN, int MODE>
__global__ __launch_bounds__(256)
void gemm_nt(const u16* __restrict__ A, const u16* __restrict__ B,
             void* __restrict__ Cv, const float* __restrict__ bias,
             int lda, int ldb, int ldc) {
    constexpr int K = 512, BK = 32, KSTEPS = K / BK;
    constexpr int ACH = BM * 4;                  // A 16B-chunks per K-step
    constexpr int NCH = (BM + BN) * 4;
    constexpr int NLD = NCH / 256;               // chunks per thread per stage
    constexpr int ABYTES = BM * 64;
    constexpr int HALF = (BM + BN) * 64;         // one buffer
    constexpr int MI = BM / 32, NJ = BN / 32;
    __shared__ __align__(16) char lds[2 * HALF];
    const int tid  = threadIdx.x;
    const int lane = tid & 63, wave = tid >> 6;
    const int quad = lane >> 4, mrow = lane & 15;
    const int wm = wave >> 1, wn = wave & 1;
    const int bm = blockIdx.y, bn = blockIdx.x;

    const char* gptr[NLD];
    char*       lptr[NLD];
    #pragma unroll
    for (int it = 0; it < NLD; ++it) {
        int c   = it * 256 + tid;                // chunk id, lane-consecutive
        int inB = (c >= ACH);
        int a   = inB ? c - ACH : c;
        int r   = a >> 2;                        // tile row
        int kc  = ((a & 3) - (r >> 1)) & 3;      // inverse swizzle
        int row = (inB ? bn * BN : bm * BM) + r;
        const u16* base = inB ? B : A;
        int ld = inB ? ldb : lda;
        gptr[it] = (const char*)(base + (size_t)row * ld + kc * 8);
        lptr[it] = (char*)lds + (it * 256 + wave * 64) * 16;   // wave-uniform
    }
    const char* aLds[MI];
    const char* bLds[NJ];
    #pragma unroll
    for (int i = 0; i < MI; ++i) {
        int ra = wm * (BM / 2) + i * 16 + mrow;
        aLds[i] = lds + (ra * 4 + ((quad + (ra >> 1)) & 3)) * 16;
    }
    #pragma unroll
    for (int j = 0; j < NJ; ++j) {
        int rb = wn * (BN / 2) + j * 16 + mrow;
        bLds[j] = lds + ABYTES + (rb * 4 + ((quad + (rb >> 1)) & 3)) * 16;
    }

    f32x4 acc[MI][NJ] = {};
    #pragma unroll
    for (int it = 0; it < NLD; ++it)             // prologue: stage 0 -> buf 0
        gload_lds16(gptr[it], lptr[it]);

    #pragma unroll
    for (int ks = 0; ks < KSTEPS; ++ks) {
        const int cur = ks & 1;
        if (ks + 1 < KSTEPS) {                   // prefetch next stage
            #pragma unroll
            for (int it = 0; it < NLD; ++it)
                gload_lds16(gptr[it] + 2 * (ks + 1) * BK, lptr[it] + (cur ^ 1) * HALF);
            asm volatile("s_waitcnt vmcnt(%0)" :: "i"(NLD) : "memory");
        } else {
            asm volatile("s_waitcnt vmcnt(0)" ::: "memory");
        }
        asm volatile("s_barrier" ::: "memory");  // stage ks visible to all

        short8 af[MI], bf[NJ];
        #pragma unroll
        for (int i = 0; i < MI; ++i) af[i] = *(const short8*)(aLds[i] + cur * HALF);
        #pragma unroll
        for (int j = 0; j < NJ; ++j) bf[j] = *(const short8*)(bLds[j] + cur * HALF);
        #pragma unroll
        for (int i = 0; i < MI; ++i)
            #pragma unroll
            for (int j = 0; j < NJ; ++j)
                acc[i][j] = __builtin_amdgcn_mfma_f32_16x16x32_bf16(af[i], bf[j], acc[i][j], 0, 0, 0);
        asm volatile("s_waitcnt lgkmcnt(0)" ::: "memory");
        asm volatile("s_barrier" ::: "memory");  // all waves done reading buf
    }

    // epilogue: D row = quad*4 + reg, col = lane&15 (m89-verified layout)
    #pragma unroll
    for (int i = 0; i < MI; ++i) {
        #pragma unroll
        for (int j = 0; j < NJ; ++j) {
            int colg = bn * BN + wn * (BN / 2) + j * 16 + mrow;
            #pragma unroll
            for (int r = 0; r < 4; ++r) {
                int rowg = bm * BM + wm * (BM / 2) + i * 16 + quad * 4 + r;
                if (MODE == 0) {
                    ((u16*)Cv)[(size_t)rowg * ldc + colg] = f2bf(acc[i][j][r]);
                } else {
                    ((float*)Cv)[(size_t)rowg * ldc + colg] = acc[i][j][r] + bias[colg];
                }
            }
        }
    }
}

// ---------------------------------------------------------------------------
// Attention: one wave per (b, h, ti).  Two-phase, branch-free slot set.
// Valid neighbor offsets (causal nb<=t <=> (df,dh,dw) lex<= 0): 9x df=-1,
// 3x (0,-1,dw), (0,0,-1), (0,0,0)  => 14 window slots + BOS = 15 (+1 pad).
// Phase 1: lane = j*4+g; 16-dim partial dot, 2-shfl reduce, batched softmax
//   (4-shfl max, ONE exp, 4-shfl sum), pe normalized by rcp(l).
// Phase 2: lane = dim; 15x (2 readlane + u16 load + fma), u32 byte offsets.
// ---------------------------------------------------------------------------
__global__ __launch_bounds__(256)
void attn_kernel(const u16* __restrict__ QKV, u16* __restrict__ O) {
    const int wid  = blockIdx.x * 4 + (threadIdx.x >> 6);
    const int lane = threadIdx.x & 63;
    const int bh = wid >> 12;            // 16
    const int ti = wid & 4095;           // 4096
    const int b = bh >> 3, h = bh & 7;
    const size_t baseQ = (size_t)b * T_TOK * NQKV;
    const size_t baseO = (size_t)b * T_TOK * DIM;

    if (ti == 0) {                        // output row 0 = bos_v
        O[baseO + h * 64 + lane] = QKV[baseQ + 1024 + h * 64 + lane];
        return;
    }
    const int t = ti - 1;                 // grid position, 0..4094
    const int f = t >> 10, hh = (t >> 5) & 31, ww = t & 31;

    const int j = lane >> 2, g = lane & 3;
    int jm1 = j - 1;
    int dh9 = ((jm1 * 11) >> 5) - 1;      // j in 1..9: (j-1)/3 - 1
    int dw9 = jm1 - (dh9 + 1) * 3 - 1;    // j in 1..9: (j-1)%3 - 1
    int df = (j >= 1 && j <= 9) ? -1 : 0;
    int dh = (j >= 1 && j <= 9) ? dh9 : ((j >= 10 && j <= 12) ? -1 : 0);
    int dw = (j >= 1 && j <= 9) ? dw9 :
             ((j >= 10 && j <= 12) ? (j - 11) : ((j == 13) ? -1 : 0));
    int nf = f + df, nh = hh + dh, nw = ww + dw;
    int valid = (nf >= 0) && ((unsigned)nh < 32u) && ((unsigned)nw < 32u)
                && (j >= 1) && (j <= 14);
    int p = valid ? (t + 1 + df * 1024 + dh * 32 + dw) : 0;   // j==0 -> BOS
    int score_on = valid || (j == 0);

    // ---- phase 1: scores
    const u16* qrow = QKV + baseQ + (size_t)(t + 1) * NQKV + h * 64 + g * 16;
    short8 q0 = *(const short8*)qrow;
    short8 q1 = *(const short8*)(qrow + 8);
    const u16* krow = QKV + baseQ + (size_t)p * NQKV + 512 + h * 64 + g * 16;
    short8 k0 = *(const short8*)krow;
    short8 k1 = *(const short8*)(krow + 8);
    float s = 0.f;
    #pragma unroll
    for (int i = 0; i < 8; ++i) {
        s = fmaf(b2f((u16)q0[i]), b2f((u16)k0[i]), s);
        s = fmaf(b2f((u16)q1[i]), b2f((u16)k1[i]), s);
    }
    s += __shfl_xor(s, 1);
    s += __shfl_xor(s, 2);                // all 4 g-lanes of slot j hold dot_j
    s *= 0.125f;                          // SCALE
    s = score_on ? s : -3.0e38f;

    float m = s;
    #pragma unroll
    for (int off = 4; off <= 32; off <<= 1) m = fmaxf(m, __shfl_xor(m, off));
    float pe = __expf(s - m);             // masked lanes -> 0
    float l = pe;
    #pragma unroll
    for (int off = 4; off <= 32; off <<= 1) l += __shfl_xor(l, off);
    float pen = pe * __frcp_rn(l);        // normalized weight, wave-wide
    u32 voff = (u32)p * 3072u;            // byte offset of V row p

    // ---- phase 2: PV, lane = dim
    float acc = 0.f;
    const char* vb = (const char*)(QKV + baseQ + 1024 + h * 64 + lane);
    #pragma unroll
    for (int jj = 0; jj < 15; ++jj) {
        u32 o = (u32)__builtin_amdgcn_readlane((int)voff, jj * 4);
        float pj = __uint_as_float(
                     (u32)__builtin_amdgcn_readlane((int)__float_as_uint(pen), jj * 4));
        float vv = b2f(*(const u16*)(vb + o));
        acc = fmaf(pj, vv, acc);
    }
    O[baseO + (size_t)ti * DIM + h * 64 + lane] = f2bf(acc);
}

// ---------------------------------------------------------------------------
// launch: cast -> gemm1 (QKV) -> attn -> gemm2 (out proj + bias)
// ws layout (bytes): xb 8M @0 | Wt 1.5M @8388608 | Wot 0.5M @9961472 |
//                    QKV 24M @10485760 | O aliases xb @0   (total ~34MB)
// ---------------------------------------------------------------------------
extern "C" void kernel_launch(void* const* d_in, const int* in_sizes, int n_in,
                              void* d_out, int out_size, void* d_ws, size_t ws_size,
                              hipStream_t stream) {
    const float* x   = (const float*)d_in[0];
    const float* Wq  = (const float*)d_in[1];
    const float* Wkv = (const float*)d_in[2];
    const float* Wo  = (const float*)d_in[3];
    const float* bo  = (const float*)d_in[4];
    float* out = (float*)d_out;
    char* ws = (char*)d_ws;

    u16* xb  = (u16*)(ws + 0);
    u16* Wt  = (u16*)(ws + 8388608);
    u16* Wot = (u16*)(ws + 9961472);
    u16* QKV = (u16*)(ws + 10485760);
    u16* O   = (u16*)(ws + 0);          // aliases xb (dead after gemm1)

    cast_all_kernel<<<dim3(4352), dim3(256), 0, stream>>>(
        (const float4*)x, Wq, Wkv, Wo, xb, Wt, Wot);
    gemm_nt<128, 128, 0><<<dim3(12, 64), dim3(256), 0, stream>>>(
        xb, Wt, (void*)QKV, nullptr, 512, 512, 1536);
    attn_kernel<<<dim3(16384), dim3(256), 0, stream>>>(QKV, O);
    gemm_nt<128, 64, 1><<<dim3(8, 64), dim3(256), 0, stream>>>(
        O, Wot, (void*)out, bo, 512, 512, 512);
}